// Round 2
// baseline (635.916 us; speedup 1.0000x reference)
//
#include <hip/hip_runtime.h>

#define Dn 200
#define Cn 8
#define Gn 10000
#define Vn 20000
#define VGn 50000
#define GLn 500
#define EPSf 1e-8f
#define ZSPLIT 8
#define CHUNK (Dn / ZSPLIT)    // 25 donors per block
#define OBS_ROW (Cn * GLn)     // 4000 floats = 16 KB
#define OBS_VEC (OBS_ROW / 4)  // 1000 float4 chunks

// Stirling series, accurate for y >= 8 (2 terms: err ~2e-8 at y=8)
__device__ __forceinline__ float stirling_lg(float y) {
    float ly  = __logf(y);
    float iv  = __builtin_amdgcn_rcpf(y);
    float iv2 = iv * iv;
    float ser = iv * fmaf(iv2, -0.00277777777778f, 0.08333333333333f);
    return fmaf(y - 0.5f, ly, -y) + 0.91893853320467274f + ser;
}

// lgamma(x) for ANY x > 0: shift by 8, then Stirling.
// Product of 8 terms folded via (x+k)(x+7-k) = q + k(7-k), q = x(x+7).
__device__ __forceinline__ float lgamma_shift8(float x) {
    const float q = x * (x + 7.0f);
    const float p = (q * (q + 6.0f)) * ((q + 10.0f) * (q + 12.0f));
    return stirling_lg(x + 8.0f) - __logf(p);
}

__global__ __launch_bounds__(256, 4) void elbo_kernel(
    const float* __restrict__ fc_log,
    const float* __restrict__ genotypes,
    const float* __restrict__ obs,
    const float* __restrict__ lib,
    const float* __restrict__ baseline_log,
    const float* __restrict__ dispersion_log,
    const int* __restrict__ v2g,
    const int* __restrict__ lv_sel,
    const int* __restrict__ v2lg,
    float* __restrict__ out)
{
    __shared__ float s_obs[OBS_ROW];     // one donor's obs row [c][gl], 16 KB
    __shared__ float s_ltab[128];        // lgamma(1+n)
    __shared__ float s_ll[CHUNK * Cn];   // log(lib) for this block's donor chunk

    const int tid = threadIdx.x;
    const int id  = blockIdx.x;
    // z -> XCD swizzle: blocks sharing a donor chunk (same z) land on the same
    // XCD (round-robin id%8), so the chunk's 2 MB genotype slice stays L2-resident.
    const int z   = id & 7;
    const int xb  = id >> 3;
    int vg = xb * 256 + tid;
    const bool active = (vg < VGn);
    if (!active) vg = VGn - 1;
    const int d0 = z * CHUNK;

    // ---- block preamble ----
    if (tid < 128) s_ltab[tid] = lgamma_shift8(1.0f + (float)tid);
    for (int idx = tid; idx < CHUNK * Cn; idx += 256)
        s_ll[idx] = __logf(lib[d0 * Cn + idx]);

    // ---- per-thread (vg) params, shared across all 8 c ----
    const int lv   = lv_sel[vg];
    const int lg   = v2lg[vg];
    const int gene = v2g[vg];

    float fc[Cn], bl[Cn], r_[Cn], K_[Cn], r2e[Cn];
    #pragma unroll
    for (int c = 0; c < Cn; ++c) {
        fc[c] = fc_log[c * VGn + vg];
        bl[c] = baseline_log[c * Gn + gene];
        const float dl   = dispersion_log[c * Gn + gene];
        const float disp = fminf(__expf(dl), 20.0f);
        const float r    = 1.0f / disp;
        r_[c]  = r;
        K_[c]  = lgamma_shift8(r) - r * __logf(r + EPSf);
        r2e[c] = r + 2.0f * EPSf;
    }

    // ---- pointers ----
    const float* gp   = genotypes + (size_t)d0 * Vn + lv;
    const float* orow = obs + (size_t)d0 * OBS_ROW;
    float*       wp   = out + ((size_t)d0 * Cn) * VGn + vg;

    // ---- prologue: prefetch donor 0's obs row into regs + g0 ----
    float4 st[4];
    #pragma unroll
    for (int k = 0; k < 4; ++k) {
        const int j = tid + 256 * k;
        if (j < OBS_VEC) st[k] = reinterpret_cast<const float4*>(orow)[j];
    }
    float g = *gp;
    gp += Vn;
    orow += OBS_ROW;

    // ---- main loop: T14 async-stage split (write-late / issue-early) ----
    for (int i = 0; i < CHUNK; ++i) {
        // write the prefetched obs row to LDS
        #pragma unroll
        for (int k = 0; k < 4; ++k) {
            const int j = tid + 256 * k;
            if (j < OBS_VEC) reinterpret_cast<float4*>(s_obs)[j] = st[k];
        }
        __syncthreads();   // also covers preamble s_ltab/s_ll on i==0

        // issue next iteration's loads; latency hides under the c-loop
        float gn = 0.0f;
        if (i + 1 < CHUNK) {
            #pragma unroll
            for (int k = 0; k < 4; ++k) {
                const int j = tid + 256 * k;
                if (j < OBS_VEC) st[k] = reinterpret_cast<const float4*>(orow)[j];
            }
            gn = *gp;
        }
        gp += Vn;
        orow += OBS_ROW;

        const float* llp = s_ll + i * Cn;
        #pragma unroll
        for (int c = 0; c < Cn; ++c) {
            const float value = s_obs[c * GLn + lg];   // LDS gather, ~random bank
            const float s  = fmaf(g, fc[c], bl[c] + llp[c]);
            const float mu = __expf(s);
            const float L  = __logf(r2e[c] + mu);
            const float rv = r_[c] + value;

            int vi = (int)value;
            vi = vi < 0 ? 0 : (vi > 127 ? 127 : vi);

            const float e = fmaf(rv, L, K_[c]) - value * s + s_ltab[vi] - lgamma_shift8(rv);
            if (active) wp[(size_t)c * VGn] = e;
        }
        wp += (size_t)Cn * VGn;
        g = gn;
        __syncthreads();   // s_obs reads done before next iter's ds_writes
    }
}

extern "C" void kernel_launch(void* const* d_in, const int* in_sizes, int n_in,
                              void* d_out, int out_size, void* d_ws, size_t ws_size,
                              hipStream_t stream) {
    const float* fc_log         = (const float*)d_in[0];
    const float* genotypes      = (const float*)d_in[1];
    const float* obs            = (const float*)d_in[2];
    const float* lib            = (const float*)d_in[3];
    const float* baseline_log   = (const float*)d_in[4];
    const float* dispersion_log = (const float*)d_in[5];
    const int* v2g    = (const int*)d_in[6];
    const int* lv_sel = (const int*)d_in[7];
    const int* v2lg   = (const int*)d_in[8];
    float* out = (float*)d_out;

    dim3 grid(((VGn + 255) / 256) * ZSPLIT, 1, 1);
    elbo_kernel<<<grid, 256, 0, stream>>>(fc_log, genotypes, obs, lib,
                                          baseline_log, dispersion_log,
                                          v2g, lv_sel, v2lg, out);
}

// Round 5
// 523.070 us; speedup vs baseline: 1.2157x; 1.2157x over previous
//
#include <hip/hip_runtime.h>

#define Dn 200
#define Cn 8
#define Gn 10000
#define Vn 20000
#define VGn 50000
#define GLn 500
#define EPSf 1e-8f
#define ZSPLIT 8
#define CHUNK (Dn / ZSPLIT)   // 25 donors per block

typedef float f2 __attribute__((ext_vector_type(2)));

// ---- scalar Stirling / lgamma (preamble only) ----
__device__ __forceinline__ float stirling_lg(float y) {
    float ly  = __logf(y);
    float iv  = __builtin_amdgcn_rcpf(y);
    float iv2 = iv * iv;
    float ser = iv * (0.08333333333333f + iv2 * (-0.00277777777778f + iv2 * 0.00079365079365f));
    return fmaf(y - 0.5f, ly, -y) + 0.91893853320467274f + ser;
}
__device__ __forceinline__ float lgamma_shift8(float x) {
    const float q = x * (x + 7.0f);
    const float p = (q * (q + 6.0f)) * ((q + 10.0f) * (q + 12.0f));
    return stirling_lg(x + 8.0f) - __logf(p);
}

__global__ __launch_bounds__(256, 6) void elbo_kernel(
    const float* __restrict__ fc_log,
    const float* __restrict__ genotypes,
    const float* __restrict__ obs,
    const float* __restrict__ lib,
    const float* __restrict__ baseline_log,
    const float* __restrict__ dispersion_log,
    const int* __restrict__ v2g,
    const int* __restrict__ lv_sel,
    const int* __restrict__ v2lg,
    float* __restrict__ out)
{
    __shared__ float s_ltab[128];        // lgamma(1+n)
    __shared__ float s_ll[CHUNK * Cn];   // log(lib) for this block's donor chunk

    const int tid = threadIdx.x;
    int vg = blockIdx.x * 256 + tid;
    const bool active = (vg < VGn);
    if (!active) vg = VGn - 1;
    const int d0 = blockIdx.z * CHUNK;

    // ---- block preamble ----
    if (tid < 128) s_ltab[tid] = lgamma_shift8(1.0f + (float)tid);
    for (int idx = tid; idx < CHUNK * Cn; idx += 256)
        s_ll[idx] = __logf(lib[d0 * Cn + idx]);

    // ---- per-thread (vg) params, shared across all 8 c ----
    const int lv   = lv_sel[vg];
    const int lg   = v2lg[vg];
    const int gene = v2g[vg];

    float fcs[Cn], bls[Cn], rs[Cn], Ks[Cn], r2s[Cn];
    #pragma unroll
    for (int c = 0; c < Cn; ++c) {
        fcs[c] = fc_log[c * VGn + vg];
        bls[c] = baseline_log[c * Gn + gene];
        const float dl   = dispersion_log[c * Gn + gene];
        const float disp = fminf(__expf(dl), 20.0f);
        const float r    = 1.0f / disp;
        rs[c]  = r;
        Ks[c]  = lgamma_shift8(r) - r * __logf(r + EPSf);
        r2s[c] = r + 2.0f * EPSf;
    }
    // pack condition params into float2 pairs (targets v_pk_* packed f32)
    f2 fc2[4], bl2[4], r2[4], K2[4], r2e2[4];
    #pragma unroll
    for (int cp = 0; cp < 4; ++cp) {
        fc2[cp]  = (f2){fcs[2*cp],  fcs[2*cp+1]};
        bl2[cp]  = (f2){bls[2*cp],  bls[2*cp+1]};
        r2[cp]   = (f2){rs[2*cp],   rs[2*cp+1]};
        K2[cp]   = (f2){Ks[2*cp],   Ks[2*cp+1]};
        r2e2[cp] = (f2){r2s[2*cp],  r2s[2*cp+1]};
    }
    __syncthreads();   // one barrier total (preamble), none in the main loop

    // ---- main loop over this block's donor chunk ----
    const float* gp = genotypes + (size_t)d0 * Vn + lv;
    const float* op = obs + (size_t)d0 * (Cn * GLn) + lg;
    float*       wp = out + ((size_t)d0 * Cn) * VGn + vg;

    #pragma unroll 2
    for (int i = 0; i < CHUNK; ++i) {
        const float g = *gp; gp += Vn;          // one genotype gather per d

        float vs[Cn];
        #pragma unroll
        for (int c = 0; c < Cn; ++c) vs[c] = op[c * GLn];
        op += Cn * GLn;

        #pragma unroll
        for (int cp = 0; cp < 4; ++cp) {
            f2 val = (f2){vs[2*cp], vs[2*cp+1]};
            f2 ll  = (f2){s_ll[i*Cn + 2*cp], s_ll[i*Cn + 2*cp+1]};

            f2 s  = g * fc2[cp] + (bl2[cp] + ll);            // packed fma
            f2 mu = (f2){__expf(s.x), __expf(s.y)};          // trans: scalar
            f2 a  = r2e2[cp] + mu;
            f2 L  = (f2){__logf(a.x), __logf(a.y)};
            f2 rv = r2[cp] + val;

            int vi0 = (int)val.x; vi0 = vi0 < 0 ? 0 : (vi0 > 127 ? 127 : vi0);
            int vi1 = (int)val.y; vi1 = vi1 < 0 ? 0 : (vi1 > 127 ? 127 : vi1);
            f2 T = (f2){s_ltab[vi0], s_ltab[vi1]};

            // lgamma_shift8 on rv, vectorized: product chain + Stirling
            f2 q   = rv * (rv + 7.0f);
            f2 p   = (q * (q + 6.0f)) * ((q + 10.0f) * (q + 12.0f));
            f2 y   = rv + 8.0f;
            f2 ly  = (f2){__logf(y.x), __logf(y.y)};
            f2 iv  = (f2){__builtin_amdgcn_rcpf(y.x), __builtin_amdgcn_rcpf(y.y)};
            f2 iv2 = iv * iv;
            f2 ser = iv * (0.08333333333333f + iv2 * (-0.00277777777778f + iv2 * 0.00079365079365f));
            f2 lp  = (f2){__logf(p.x), __logf(p.y)};
            f2 lgrv = (y - 0.5f) * ly - y + (0.91893853320467274f + ser) - lp;

            f2 e = rv * L + K2[cp] - val * s + T - lgrv;

            if (active) {
                wp[(size_t)(2*cp)   * VGn] = e.x;
                wp[(size_t)(2*cp+1) * VGn] = e.y;
            }
        }
        wp += (size_t)Cn * VGn;
    }
}

extern "C" void kernel_launch(void* const* d_in, const int* in_sizes, int n_in,
                              void* d_out, int out_size, void* d_ws, size_t ws_size,
                              hipStream_t stream) {
    const float* fc_log         = (const float*)d_in[0];
    const float* genotypes      = (const float*)d_in[1];
    const float* obs            = (const float*)d_in[2];
    const float* lib            = (const float*)d_in[3];
    const float* baseline_log   = (const float*)d_in[4];
    const float* dispersion_log = (const float*)d_in[5];
    const int* v2g    = (const int*)d_in[6];
    const int* lv_sel = (const int*)d_in[7];
    const int* v2lg   = (const int*)d_in[8];
    float* out = (float*)d_out;

    dim3 grid((VGn + 255) / 256, 1, ZSPLIT);
    elbo_kernel<<<grid, 256, 0, stream>>>(fc_log, genotypes, obs, lib,
                                          baseline_log, dispersion_log,
                                          v2g, lv_sel, v2lg, out);
}